// Round 3
// baseline (1218.423 us; speedup 1.0000x reference)
//
#include <hip/hip_runtime.h>

// ResidualBlock: per-voxel MLP, all convs are 1x1x1.
// x: [B=2][C=32][S=128^3] fp32, out: [B][S] fp32.
// h1 = relu(w1 @ x + b1)  (64)
// h2 = w2 @ h1 + b2       (32)
// out = w_out . (h2 + x) + b_out

#define S_SHIFT 21
#define SVOL (1 << S_SHIFT)   // 128^3 = 2097152
#define C_IN 32
#define C_HID 64

__global__ void resblock_f32(
    const float* __restrict__ x,
    const float* __restrict__ w1,
    const float* __restrict__ b1,
    const float* __restrict__ w2,
    const float* __restrict__ b2,
    const float* __restrict__ w_out,
    const float* __restrict__ b_out,
    float* __restrict__ out,
    int nslots)
{
    // Weights staged in LDS; all compute-loop reads are wave-uniform (broadcast).
    __shared__ float w1s[C_HID][C_IN];   // w1s[o][c]  = w1[o*32+c]      (8 KB)
    __shared__ float w2ts[C_HID][C_IN];  // w2ts[o][j] = w2[j*64+o]      (8 KB, transposed)
    __shared__ float b1s[C_HID];
    __shared__ float b2s[C_IN];
    __shared__ float wouts[C_IN];
    __shared__ float bouts;

    for (int idx = threadIdx.x; idx < C_HID * C_IN; idx += blockDim.x) {
        w1s[idx >> 5][idx & 31] = w1[idx];
        int j = idx >> 6;        // w2 is [32][64] row-major: w2[j*64+o]
        int o = idx & 63;
        w2ts[o][j] = w2[idx];
    }
    if (threadIdx.x < C_HID) b1s[threadIdx.x] = b1[threadIdx.x];
    if (threadIdx.x < C_IN) {
        b2s[threadIdx.x]   = b2[threadIdx.x];
        wouts[threadIdx.x] = w_out[threadIdx.x];
    }
    if (threadIdx.x == 0) bouts = b_out[0];
    __syncthreads();

    const int stride = gridDim.x * blockDim.x;
    for (int i = blockIdx.x * blockDim.x + threadIdx.x; i < nslots; i += stride) {
        const int b = i >> S_SHIFT;
        const int s = i & (SVOL - 1);
        const float* xp = x + (((size_t)b << (S_SHIFT + 5)) + (size_t)s);

        // 32 coalesced channel loads (consecutive threads -> consecutive s)
        float xv[C_IN];
        #pragma unroll
        for (int c = 0; c < C_IN; ++c) xv[c] = xp[(size_t)c << S_SHIFT];

        float h2[C_IN];
        #pragma unroll
        for (int c = 0; c < C_IN; ++c) h2[c] = b2s[c];

        #pragma unroll 4
        for (int o = 0; o < C_HID; ++o) {
            // h1[o] dot product: 4 independent partial chains (break FMA dep chain)
            float t0 = 0.f, t1 = 0.f, t2 = 0.f, t3 = 0.f;
            #pragma unroll
            for (int c = 0; c < 8; ++c) {
                t0 = fmaf(w1s[o][c],      xv[c],      t0);
                t1 = fmaf(w1s[o][c + 8],  xv[c + 8],  t1);
                t2 = fmaf(w1s[o][c + 16], xv[c + 16], t2);
                t3 = fmaf(w1s[o][c + 24], xv[c + 24], t3);
            }
            float t = b1s[o] + ((t0 + t1) + (t2 + t3));
            t = fmaxf(t, 0.0f);
            // h2 += w2[:, o] * relu(h1[o])  — 32 independent FMAs
            #pragma unroll
            for (int j = 0; j < C_IN; ++j) h2[j] = fmaf(w2ts[o][j], t, h2[j]);
        }

        // out = w_out . (h2 + x) + b_out, 4-way tree
        float a0 = 0.f, a1 = 0.f, a2 = 0.f, a3 = 0.f;
        #pragma unroll
        for (int j = 0; j < 8; ++j) {
            a0 = fmaf(wouts[j],      h2[j]      + xv[j],      a0);
            a1 = fmaf(wouts[j + 8],  h2[j + 8]  + xv[j + 8],  a1);
            a2 = fmaf(wouts[j + 16], h2[j + 16] + xv[j + 16], a2);
            a3 = fmaf(wouts[j + 24], h2[j + 24] + xv[j + 24], a3);
        }
        out[i] = bouts + ((a0 + a1) + (a2 + a3));
    }
}

extern "C" void kernel_launch(void* const* d_in, const int* in_sizes, int n_in,
                              void* d_out, int out_size, void* d_ws, size_t ws_size,
                              hipStream_t stream) {
    const float* x     = (const float*)d_in[0];
    const float* w1    = (const float*)d_in[1];
    const float* b1    = (const float*)d_in[2];
    const float* w2    = (const float*)d_in[3];
    const float* b2    = (const float*)d_in[4];
    const float* w_out = (const float*)d_in[5];
    const float* b_out = (const float*)d_in[6];
    float* out = (float*)d_out;

    const int nslots = out_size;          // 2 * 128^3 = 4194304
    dim3 grid(4096), block(256);          // grid-stride: 4 voxels/thread
    hipLaunchKernelGGL(resblock_f32, grid, block, 0, stream,
                       x, w1, b1, w2, b2, w_out, b_out, out, nslots);
}

// Round 8
// 805.175 us; speedup vs baseline: 1.5132x; 1.5132x over previous
//
#include <hip/hip_runtime.h>

// ResidualBlock, folded form:
//   v = w2^T w_out  (64), c0 = b_out + w_out . b2
//   out = sum_o v[o] * relu(w1[o].x + b1[o]) + w_out . x + c0
// This removes the h2[32] accumulator and the second matmul entirely:
// 4128 -> ~2144 FMA/voxel, and kills the register spills seen in round 3
// (VGPR=64 cap -> 244 MiB scratch writes).

#define S_SHIFT 21
#define SVOL (1 << S_SHIFT)   // 128^3
#define C_IN 32
#define C_HID 64
#define VPT 4                 // voxels per thread (float4 loads/stores)

__global__ __launch_bounds__(256, 2)
void resblock_folded(
    const float* __restrict__ x,
    const float* __restrict__ w1,
    const float* __restrict__ b1,
    const float* __restrict__ w2,
    const float* __restrict__ b2,
    const float* __restrict__ w_out,
    const float* __restrict__ b_out,
    float* __restrict__ out,
    int nslots)
{
    __shared__ float w1s[C_HID][C_IN];  // 8 KB, read wave-uniform (broadcast)
    __shared__ float b1s[C_HID];
    __shared__ float vs[C_HID];         // v = w2^T w_out
    __shared__ float wouts[C_IN];
    __shared__ float c0s;

    const int tid = threadIdx.x;
    for (int idx = tid; idx < C_HID * C_IN; idx += blockDim.x)
        w1s[idx >> 5][idx & 31] = w1[idx];   // coalesced, conflict-free
    if (tid < C_HID) {
        b1s[tid] = b1[tid];
        float v = 0.f;
        #pragma unroll
        for (int j = 0; j < C_IN; ++j)       // w2[j][tid], coalesced across tid
            v = fmaf(w_out[j], w2[j * C_HID + tid], v);
        vs[tid] = v;
    }
    if (tid < C_IN) wouts[tid] = w_out[tid];
    if (tid == 0) {
        float c0 = b_out[0];
        #pragma unroll
        for (int j = 0; j < C_IN; ++j) c0 = fmaf(w_out[j], b2[j], c0);
        c0s = c0;
    }
    __syncthreads();

    const int g  = blockIdx.x * blockDim.x + tid;  // voxel-group id
    const int i0 = g * VPT;
    if (i0 >= nslots) return;
    const int b = i0 >> S_SHIFT;
    const int s = i0 & (SVOL - 1);
    const float* xp = x + ((size_t)b << (S_SHIFT + 5)) + (size_t)s;

    // 32 coalesced float4 channel loads (16 B/lane sweet spot)
    float4 xv[C_IN];
    #pragma unroll
    for (int c = 0; c < C_IN; ++c)
        xv[c] = *reinterpret_cast<const float4*>(xp + ((size_t)c << S_SHIFT));

    // acc = c0 + w_out . x   (fp32-exact residual path)
    const float c0 = c0s;
    float a0 = c0, a1 = c0, a2 = c0, a3 = c0;
    #pragma unroll
    for (int j = 0; j < C_IN; ++j) {
        const float wj = wouts[j];
        a0 = fmaf(wj, xv[j].x, a0);
        a1 = fmaf(wj, xv[j].y, a1);
        a2 = fmaf(wj, xv[j].z, a2);
        a3 = fmaf(wj, xv[j].w, a3);
    }

    // acc += sum_o v[o] * relu(w1[o].x + b1[o]); 4 voxels = 4 independent chains
    #pragma unroll 4
    for (int o = 0; o < C_HID; ++o) {
        float t0 = 0.f, t1 = 0.f, t2 = 0.f, t3 = 0.f;
        #pragma unroll
        for (int c = 0; c < C_IN; ++c) {
            const float w = w1s[o][c];       // ds_read_b128 x8 per o, broadcast
            t0 = fmaf(w, xv[c].x, t0);
            t1 = fmaf(w, xv[c].y, t1);
            t2 = fmaf(w, xv[c].z, t2);
            t3 = fmaf(w, xv[c].w, t3);
        }
        const float bo = b1s[o];
        const float vo = vs[o];
        a0 = fmaf(vo, fmaxf(t0 + bo, 0.f), a0);
        a1 = fmaf(vo, fmaxf(t1 + bo, 0.f), a1);
        a2 = fmaf(vo, fmaxf(t2 + bo, 0.f), a2);
        a3 = fmaf(vo, fmaxf(t3 + bo, 0.f), a3);
    }

    *reinterpret_cast<float4*>(out + i0) = make_float4(a0, a1, a2, a3);
}

extern "C" void kernel_launch(void* const* d_in, const int* in_sizes, int n_in,
                              void* d_out, int out_size, void* d_ws, size_t ws_size,
                              hipStream_t stream) {
    const float* x     = (const float*)d_in[0];
    const float* w1    = (const float*)d_in[1];
    const float* b1    = (const float*)d_in[2];
    const float* w2    = (const float*)d_in[3];
    const float* b2    = (const float*)d_in[4];
    const float* w_out = (const float*)d_in[5];
    const float* b_out = (const float*)d_in[6];
    float* out = (float*)d_out;

    const int nslots = out_size;                   // 4194304
    const int nblocks = nslots / (256 * VPT);      // 4096: one group per thread
    hipLaunchKernelGGL(resblock_folded, dim3(nblocks), dim3(256), 0, stream,
                       x, w1, b1, w2, b2, w_out, b_out, out, nslots);
}